// Round 6
// baseline (880.372 us; speedup 1.0000x reference)
//
#include <hip/hip_runtime.h>
#include <stdint.h>

#define T_STEPS 500
#define NBATCH  128
#define NIN     784
#define KPAD    832
#define NH      1024
#define NSL     102
#define DECAY   0.8807970779778823f

typedef __attribute__((ext_vector_type(8))) short short8;
typedef __attribute__((ext_vector_type(4))) float f32x4;
typedef unsigned int u32;
typedef unsigned long long u64;

static __device__ __forceinline__ unsigned short f2bf(float f) {
  union { float f; u32 u; } v; v.f = f;
  u32 r = (v.u + 0x7FFFu + ((v.u >> 16) & 1u)) >> 16;
  return (unsigned short)r;
}
static __device__ __forceinline__ float uf(u32 u) {
  union { u32 u; float f; } v; v.u = u; return v.f;
}
static __device__ __forceinline__ u32 fu(float f) {
  union { float f; u32 u; } v; v.f = f; return v.u;
}
static __device__ __forceinline__ void gl16(const void* g, void* l) {
  __builtin_amdgcn_global_load_lds((const __attribute__((address_space(1))) u32*)g,
                                   (__attribute__((address_space(3))) u32*)l, 16, 0, 0);
}

// ---- prep: transpose fc1 -> fc1T[1024][832] bf16 (K zero-padded) -----------
__global__ __launch_bounds__(256) void prep_kernel(
    const float* __restrict__ fc1, unsigned short* __restrict__ fc1T,
    float* __restrict__ out_last) {
  __shared__ float tile[32][33];
  const int bx = blockIdx.x;  // 26 k-blocks x 32 n-blocks
  const int kb = (bx % 26) * 32, nb = (bx / 26) * 32;
  const int tx = threadIdx.x & 31, ty = threadIdx.x >> 5;
#pragma unroll
  for (int i = 0; i < 4; ++i) {
    int k = kb + ty + i * 8, n = nb + tx;
    tile[ty + i * 8][tx] = (k < NIN) ? fc1[(size_t)k * NH + n] : 0.0f;
  }
  __syncthreads();
#pragma unroll
  for (int i = 0; i < 4; ++i) {
    int n = nb + ty + i * 8, k = kb + tx;
    fc1T[(size_t)n * KPAD + k] = f2bf(tile[tx][ty + i * 8]);
  }
  if (bx == 0 && threadIdx.x == 0) *out_last = 500.0f;
}

// ---- GEMM (BM=128, BN=128, BK=64, bf16 A+B in LDS) + embedded colsum -------
// A: coalesced fp32 loads -> in-reg v_perm bf16 -> one swizzled ds_write_b128.
// B: gl16 with XOR-swizzled global chunk. Both LDS layouts: [row][64] bf16,
// 8x16B chunks, phys = g ^ (row&7) -> all b128 reads/writes <=2-way (free).
__global__ __launch_bounds__(256, 3) void gemm_kernel(
    const float* __restrict__ x, const unsigned short* __restrict__ fc1T,
    const float* __restrict__ wrec, float* __restrict__ colsum,
    unsigned short* __restrict__ curq) {
  if (blockIdx.y == 500) {  // ---- colsum: 4 blocks of 256 cols ----
    if (blockIdx.x >= 4) return;
    const int h = blockIdx.x * 256 + threadIdx.x;
    float s0 = 0.f, s1 = 0.f, s2 = 0.f, s3 = 0.f,
          s4 = 0.f, s5 = 0.f, s6 = 0.f, s7 = 0.f;
    for (int j = 0; j < NH; j += 8) {
      s0 += wrec[(size_t)(j + 0) * NH + h];
      s1 += wrec[(size_t)(j + 1) * NH + h];
      s2 += wrec[(size_t)(j + 2) * NH + h];
      s3 += wrec[(size_t)(j + 3) * NH + h];
      s4 += wrec[(size_t)(j + 4) * NH + h];
      s5 += wrec[(size_t)(j + 5) * NH + h];
      s6 += wrec[(size_t)(j + 6) * NH + h];
      s7 += wrec[(size_t)(j + 7) * NH + h];
    }
    colsum[h] = ((s0 + s1) + (s2 + s3)) + ((s4 + s5) + (s6 + s7));
    return;
  }

  __shared__ __align__(16) unsigned short Aq[128 * 64];  // 16 KB
  __shared__ __align__(16) unsigned short Bs[128 * 64];  // 16 KB

  const int tid = threadIdx.x;
  const int n0 = blockIdx.x * 128, m0 = blockIdx.y * 128;
  const int lane = tid & 63, wave = tid >> 6;
  const int wr = (wave >> 1) * 64, wc = (wave & 1) * 64;
  const int l16 = lane & 15, q = lane >> 4;

  const int ar = tid >> 3;  // A staging: row-in-group 0..31
  const int ac = tid & 7;   // A staging: bf16 16B-chunk 0..7 (k = ac*8..+7)

  f32x4 acc[4][4];
  const f32x4 z4 = {0.f, 0.f, 0.f, 0.f};
#pragma unroll
  for (int i = 0; i < 4; ++i)
#pragma unroll
    for (int j = 0; j < 4; ++j) acc[i][j] = z4;

  for (int k0 = 0; k0 < KPAD; k0 += 64) {
    // --- A: issue all fp32 loads first (vmcnt leaves gl16 outstanding) ---
    float4 fa[4][2];
    const bool aval = (k0 + ac * 8) < NIN;  // whole 8-float chunk valid
#pragma unroll
    for (int i = 0; i < 4; ++i) {
      if (aval) {
        const float4* src =
            (const float4*)(x + (size_t)(m0 + i * 32 + ar) * NIN + k0 + ac * 8);
        fa[i][0] = src[0];
        fa[i][1] = src[1];
      } else {
        fa[i][0] = make_float4(0.f, 0.f, 0.f, 0.f);
        fa[i][1] = make_float4(0.f, 0.f, 0.f, 0.f);
      }
    }
    // --- B: async global->LDS, swizzled source chunk ---
#pragma unroll
    for (int l = 0; l < 4; ++l) {
      const int rbase = wave * 32 + l * 8;
      const int row = rbase + (lane >> 3);
      const int g = (lane & 7) ^ (row & 7);
      gl16(fc1T + (size_t)(n0 + row) * KPAD + k0 + g * 8, &Bs[rbase * 64]);
    }
    // --- A: convert + swizzled ds_write_b128 ---
#pragma unroll
    for (int i = 0; i < 4; ++i) {
      union { short8 s; u32 u[4]; } p;
      p.u[0] = __builtin_amdgcn_perm(fu(fa[i][0].y), fu(fa[i][0].x), 0x07060302u);
      p.u[1] = __builtin_amdgcn_perm(fu(fa[i][0].w), fu(fa[i][0].z), 0x07060302u);
      p.u[2] = __builtin_amdgcn_perm(fu(fa[i][1].y), fu(fa[i][1].x), 0x07060302u);
      p.u[3] = __builtin_amdgcn_perm(fu(fa[i][1].w), fu(fa[i][1].z), 0x07060302u);
      const int row = i * 32 + ar;
      *(short8*)&Aq[row * 64 + (ac ^ (row & 7)) * 8] = p.s;
    }
    __syncthreads();

#pragma unroll
    for (int h = 0; h < 2; ++h) {
      short8 av[4], bv[4];
#pragma unroll
      for (int i = 0; i < 4; ++i) {
        const int r = wr + i * 16 + l16;
        av[i] = *(const short8*)&Aq[r * 64 + ((h * 4 + q) ^ (r & 7)) * 8];
      }
#pragma unroll
      for (int j = 0; j < 4; ++j) {
        const int r = wc + j * 16 + l16;
        bv[j] = *(const short8*)&Bs[r * 64 + ((h * 4 + q) ^ (r & 7)) * 8];
      }
#pragma unroll
      for (int i = 0; i < 4; ++i)
#pragma unroll
        for (int j = 0; j < 4; ++j)
          acc[i][j] = __builtin_amdgcn_mfma_f32_16x16x32_bf16(av[i], bv[j],
                                                              acc[i][j], 0, 0, 0);
    }
    __syncthreads();
  }

  // C/D layout: col = lane&15, row = q*4 + reg
#pragma unroll
  for (int i = 0; i < 4; ++i)
#pragma unroll
    for (int j = 0; j < 4; ++j) {
      const int row = m0 + wr + i * 16 + q * 4;
      const int col = n0 + wc + j * 16 + l16;
#pragma unroll
      for (int rr = 0; rr < 4; ++rr)
        curq[(size_t)(row + rr) * NH + col] = f2bf(acc[i][j][rr]);
    }
}

// ---- scan: one wave/batch, zero barriers, macro pipeline (no arrays of
// buffers, no by-ref rotation -> nothing can fall to scratch) ----------------
#define LOADROW(T, QA, QB)                                              \
  {                                                                     \
    const uint4* _p = (const uint4*)&curq[(rowbase + (T)) * NH + h0];   \
    (QA) = _p[0];                                                       \
    (QB) = _p[1];                                                       \
  }

#define STEP(T, QA, QB)                                                       \
  {                                                                           \
    if (__builtin_expect(pend != 0ull, 0)) {                                  \
      if (__popcll(pend) >= 48) { /* burst: colsum minus silent rows */       \
        _Pragma("unroll") for (int c = 0; c < 16; c += 4) {                   \
          const float4 cs = *(const float4*)&colsum[h0 + c];                  \
          rs[c] = cs.x; rs[c + 1] = cs.y; rs[c + 2] = cs.z; rs[c + 3] = cs.w; \
        }                                                                     \
        const u32 myz = (~spbits) & 0xFFFFu;                                  \
        u64 zm = __ballot(myz != 0);                                          \
        while (zm) {                                                          \
          const int l = __builtin_ctzll(zm); zm &= zm - 1;                    \
          u32 zb = __shfl(myz, l, 64);                                        \
          while (zb) {                                                        \
            const int c = __builtin_ctz(zb); zb &= zb - 1;                    \
            const float* w = &wrec[(size_t)(l * 16 + c) * NH + h0];           \
            _Pragma("unroll") for (int qq = 0; qq < 4; ++qq) {                \
              const float4 wv = *(const float4*)(w + 4 * qq);                 \
              rs[4 * qq] -= wv.x; rs[4 * qq + 1] -= wv.y;                     \
              rs[4 * qq + 2] -= wv.z; rs[4 * qq + 3] -= wv.w;                 \
            }                                                                 \
          }                                                                   \
        }                                                                     \
      } else {                                                                \
        u64 dm = pend;                                                        \
        while (dm) {                                                          \
          const int l = __builtin_ctzll(dm); dm &= dm - 1;                    \
          const u32 pk = __shfl(chgpack, l, 64);                              \
          u32 cbits = pk >> 16;                                               \
          while (cbits) {                                                     \
            const int c = __builtin_ctz(cbits); cbits &= cbits - 1;           \
            const float s = ((pk >> c) & 1u) ? 1.0f : -1.0f;                  \
            const float* w = &wrec[(size_t)(l * 16 + c) * NH + h0];           \
            _Pragma("unroll") for (int qq = 0; qq < 4; ++qq) {                \
              const float4 wv = *(const float4*)(w + 4 * qq);                 \
              rs[4 * qq]     = fmaf(s, wv.x, rs[4 * qq]);                     \
              rs[4 * qq + 1] = fmaf(s, wv.y, rs[4 * qq + 1]);                 \
              rs[4 * qq + 2] = fmaf(s, wv.z, rs[4 * qq + 2]);                 \
              rs[4 * qq + 3] = fmaf(s, wv.w, rs[4 * qq + 3]);                 \
            }                                                                 \
          }                                                                   \
        }                                                                     \
      }                                                                       \
      pend = 0;                                                               \
    }                                                                         \
    const u32 dw[8] = {(QA).x, (QA).y, (QA).z, (QA).w,                        \
                       (QB).x, (QB).y, (QB).z, (QB).w};                       \
    float cin[16];                                                            \
    _Pragma("unroll") for (int k = 0; k < 8; ++k) {                           \
      cin[2 * k]     = uf(dw[k] << 16);                                       \
      cin[2 * k + 1] = uf(dw[k] & 0xFFFF0000u);                               \
    }                                                                         \
    u32 newbits = 0;                                                          \
    float ns[16];                                                             \
    _Pragma("unroll") for (int c = 0; c < 16; ++c) {                          \
      const float f = fmaf(-DECAY, sp[c], DECAY);                             \
      mem[c] = fmaf(mem[c], f, cin[c] + rs[c]);                               \
      const bool fire = mem[c] >= 1.0f;                                       \
      ns[c] = fire ? 1.0f : 0.0f;                                             \
      newbits |= fire ? (1u << c) : 0u;                                       \
    }                                                                         \
    if (lane < 7) {                                                           \
      float2* o = (float2*)(out + (rowbase + (T)) * NSL + h0);                \
      const int n2 = (lane == 6) ? 3 : 8;                                     \
      _Pragma("unroll") for (int k = 0; k < 8; ++k)                           \
        if (k < n2) o[k] = make_float2(ns[2 * k], ns[2 * k + 1]);             \
    }                                                                         \
    const u32 chg = spbits ^ newbits;                                         \
    pend = __ballot(chg != 0);                                                \
    chgpack = (chg << 16) | newbits;                                          \
    spbits = newbits;                                                         \
    _Pragma("unroll") for (int c = 0; c < 16; ++c) sp[c] = ns[c];             \
  }

__global__ __launch_bounds__(64, 1) void scan_kernel(
    const unsigned short* __restrict__ curq, const float* __restrict__ wrec,
    const float* __restrict__ colsum, float* __restrict__ out) {
  const int b = blockIdx.x;
  const unsigned lane = threadIdx.x;
  const int h0 = (int)lane * 16;
  const size_t rowbase = (size_t)b * T_STEPS;

  float mem[16], rs[16], sp[16];
#pragma unroll
  for (int c = 0; c < 16; ++c) { mem[c] = 0.f; rs[c] = 0.f; sp[c] = 0.f; }
  u32 spbits = 0, chgpack = 0;
  u64 pend = 0;

  uint4 p0a, p0b, p1a, p1b, p2a, p2b, p3a, p3b;
  LOADROW(0, p0a, p0b)
  LOADROW(1, p1a, p1b)
  LOADROW(2, p2a, p2b)
  LOADROW(3, p3a, p3b)

#pragma unroll 1
  for (int tb = 0; tb < T_STEPS - 4; tb += 4) {  // tb = 0..492
    STEP(tb + 0, p0a, p0b)
    LOADROW(tb + 4, p0a, p0b)
    STEP(tb + 1, p1a, p1b)
    LOADROW(tb + 5, p1a, p1b)
    STEP(tb + 2, p2a, p2b)
    LOADROW(tb + 6, p2a, p2b)
    STEP(tb + 3, p3a, p3b)
    LOADROW(tb + 7, p3a, p3b)
  }
  STEP(T_STEPS - 4, p0a, p0b)
  STEP(T_STEPS - 3, p1a, p1b)
  STEP(T_STEPS - 2, p2a, p2b)
  STEP(T_STEPS - 1, p3a, p3b)
}

extern "C" void kernel_launch(void* const* d_in, const int* in_sizes, int n_in,
                              void* d_out, int out_size, void* d_ws, size_t ws_size,
                              hipStream_t stream) {
  const float* x    = (const float*)d_in[0];  // [128][500][784] fp32
  const float* fc1  = (const float*)d_in[1];  // [784][1024] fp32
  const float* wrec = (const float*)d_in[2];  // [1024][1024] fp32
  float* out = (float*)d_out;                 // [128*500*102] + [1]

  unsigned short* fc1T = (unsigned short*)d_ws;                     // 1,703,936 B
  float* colsum = (float*)((char*)d_ws + 1703936);                  // 4,096 B
  unsigned short* curq = (unsigned short*)((char*)d_ws + 1708032);  // 131,072,000 B

  prep_kernel<<<dim3(26 * 32), 256, 0, stream>>>(fc1, fc1T, out + (out_size - 1));
  gemm_kernel<<<dim3(8, 501), 256, 0, stream>>>(x, fc1T, wrec, colsum, curq);
  scan_kernel<<<dim3(NBATCH), 64, 0, stream>>>(curq, wrec, colsum, out);
}